// Round 2
// baseline (2495.701 us; speedup 1.0000x reference)
//
#include <hip/hip_runtime.h>
#include <hip/hip_bf16.h>
#include <math.h>

// Qwen3 MoE block: B=1, S=1024, H=2048, E=64, I=768, top-k=8
#define TT 1024
#define HH 2048
#define EE 64
#define II 768
#define TOPK 8
#define NPAIR (TT * TOPK)

typedef __attribute__((ext_vector_type(8))) short bfrag;   // 8 bf16 (4 VGPRs)
typedef __attribute__((ext_vector_type(4))) float ffrag;   // 4 fp32 acc

// RNE fp32 -> bf16 (inputs are finite; no NaN handling needed)
__device__ inline unsigned short f2bf(float f) {
    union { float f; unsigned u; } v; v.f = f;
    unsigned u = v.u;
    u += 0x7fffu + ((u >> 16) & 1u);
    return (unsigned short)(u >> 16);
}
__device__ inline unsigned packbf(float a, float b) {
    return (unsigned)f2bf(a) | ((unsigned)f2bf(b) << 16);
}

// ---------------------------------------------------------------------------
// counts zeroing (d_ws is re-poisoned 0xAA before every launch)
// ---------------------------------------------------------------------------
__global__ void zero_counts(int* __restrict__ counts) {
    counts[threadIdx.x] = 0;
}

// ---------------------------------------------------------------------------
// Gating: one 64-thread block per token; thread e computes the logit for
// expert e; lane 0 does top-8 + softmax-over-selected (== softmax+renorm of
// the reference) and scatters into per-expert lists.
// ---------------------------------------------------------------------------
__global__ __launch_bounds__(64) void gate_kernel(
    const float* __restrict__ x, const float* __restrict__ gw,
    int* __restrict__ counts, int* __restrict__ list_pair, float* __restrict__ list_wt)
{
    int t = blockIdx.x;
    int e = threadIdx.x;
    const float4* xr = (const float4*)(x + (size_t)t * HH);
    const float4* gr = (const float4*)(gw + (size_t)e * HH);
    float acc = 0.f;
    #pragma unroll 4
    for (int h = 0; h < HH / 4; ++h) {
        float4 a = xr[h], b = gr[h];
        acc += a.x * b.x + a.y * b.y + a.z * b.z + a.w * b.w;
    }
    __shared__ float slog[EE];
    slog[e] = acc;
    __syncthreads();
    if (e == 0) {
        float lv[TOPK]; int li[TOPK];
        unsigned long long used = 0ULL;
        for (int k = 0; k < TOPK; ++k) {
            float best = -INFINITY; int bi = 0;
            for (int j = 0; j < EE; ++j)
                if (!((used >> j) & 1ULL) && slog[j] > best) { best = slog[j]; bi = j; }
            used |= 1ULL << bi;
            lv[k] = best; li[k] = bi;
        }
        float mx = lv[0], w[TOPK], s = 0.f;
        for (int k = 0; k < TOPK; ++k) { w[k] = __expf(lv[k] - mx); s += w[k]; }
        float inv = 1.f / s;
        for (int k = 0; k < TOPK; ++k) {
            int ex = li[k];
            int pos = atomicAdd(&counts[ex], 1);
            list_pair[ex * TT + pos] = t * TOPK + k;
            list_wt[ex * TT + pos]  = w[k] * inv;
        }
    }
}

// ---------------------------------------------------------------------------
// MFMA fragment layouts (16x16x32 bf16, HW-verified m89/m91/m120):
//   A frag: A[m = lane&15][k = (lane>>4)*8 + j], j=0..7  (8 bf16, b128)
//   B frag: B[k = (lane>>4)*8 + j][n = lane&15]
//   C/D:    col = lane&15, row = (lane>>4)*4 + reg
// LDS holds tiles in fragment-direct order: region[tile16][s][lane][8 halves]
// so fragment reads are lane-consecutive 16B (conflict-free b128).
// slot(tile,s,lane) half-index = ((tile*2+s)*64 + lane)*8
// ---------------------------------------------------------------------------

#define UP_NT 6   // 768/128
#define UP_MT 8   // worst-case ceil(1024/128)

__global__ __launch_bounds__(256, 2) void up_mfma(
    const float* __restrict__ x, const float* __restrict__ w1, const float* __restrict__ w3,
    const int* __restrict__ counts, const int* __restrict__ list_pair, const float* __restrict__ list_wt,
    __hip_bfloat16* __restrict__ act)
{
    int bx = blockIdx.x;
    int e   = bx / (UP_MT * UP_NT);
    int rem = bx % (UP_MT * UP_NT);
    int mt = rem / UP_NT, nt = rem % UP_NT;
    int Ne = counts[e];
    int m0 = mt * 128;
    if (m0 >= Ne) return;
    int n0 = nt * 128;

    __shared__ alignas(16) short Xf[8192];    // 16 KB
    __shared__ alignas(16) short W1f[8192];
    __shared__ alignas(16) short W3f[8192];
    __shared__ int   s_pair[128];
    __shared__ float s_wt[128];

    const int tid = threadIdx.x;
    const int lane = tid & 63;
    const int w = tid >> 6;
    const int wm = (w & 1) * 64, wn = (w >> 1) * 64;

    if (tid < 128) {
        int m = m0 + tid;
        s_pair[tid] = (m < Ne) ? list_pair[e * TT + m] : 0;
        s_wt[tid]   = (m < Ne) ? list_wt[e * TT + m]   : 0.f;
    }

    ffrag accg[4][4], accu[4][4];
    #pragma unroll
    for (int i = 0; i < 4; ++i)
        #pragma unroll
        for (int j = 0; j < 4; ++j) { accg[i][j] = (ffrag)0.f; accu[i][j] = (ffrag)0.f; }

    for (int k0 = 0; k0 < HH; k0 += 64) {
        __syncthreads();   // s_pair ready (1st iter); prior MFMA reads done
        {   // stage X tile: 2 threads per m-row, fp32->bf16
            int m = tid >> 1, c = tid & 1;
            int tok = s_pair[m] >> 3;
            const float* src = x + (size_t)tok * HH + k0 + c * 32;
            int mtile = m >> 4, mlane = m & 15;
            #pragma unroll
            for (int r = 0; r < 8; ++r) {
                int k = c * 32 + r * 4;
                float4 v = *(const float4*)(src + r * 4);
                int s = k >> 5, q = (k >> 3) & 3, j = k & 7;
                int slot = ((mtile * 2 + s) * 64 + mlane + q * 16) * 8 + j;
                *(uint2*)&Xf[slot] = make_uint2(packbf(v.x, v.y), packbf(v.z, v.w));
            }
        }
        {   // stage W1/W3 tiles: transpose-pack k-pairs into fragment order
            int n = tid & 127, kp2 = tid >> 7;
            int ntile = n >> 4, nl = n & 15;
            const float* s1 = w1 + ((size_t)e * HH + k0 + kp2 * 32) * II + n0 + n;
            const float* s3 = w3 + ((size_t)e * HH + k0 + kp2 * 32) * II + n0 + n;
            #pragma unroll
            for (int r = 0; r < 16; ++r) {
                int kp = kp2 * 16 + r;          // 0..31, k = 2*kp
                int k = kp * 2;
                float a1 = s1[(size_t)(2 * r) * II],     b1 = s1[(size_t)(2 * r + 1) * II];
                float a3 = s3[(size_t)(2 * r) * II],     b3 = s3[(size_t)(2 * r + 1) * II];
                int s = k >> 5, q = (k >> 3) & 3;
                int slot = ((ntile * 2 + s) * 64 + nl + q * 16) * 8 + (kp & 3) * 2;
                *(unsigned*)&W1f[slot] = packbf(a1, b1);
                *(unsigned*)&W3f[slot] = packbf(a3, b3);
            }
        }
        __syncthreads();
        #pragma unroll
        for (int s = 0; s < 2; ++s) {
            bfrag a[4];
            #pragma unroll
            for (int mi = 0; mi < 4; ++mi)
                a[mi] = *(const bfrag*)&Xf[(((wm >> 4) + mi) * 2 + s) * 64 * 8 + lane * 8];
            #pragma unroll
            for (int ni = 0; ni < 4; ++ni) {
                bfrag b1 = *(const bfrag*)&W1f[(((wn >> 4) + ni) * 2 + s) * 64 * 8 + lane * 8];
                bfrag b3 = *(const bfrag*)&W3f[(((wn >> 4) + ni) * 2 + s) * 64 * 8 + lane * 8];
                #pragma unroll
                for (int mi = 0; mi < 4; ++mi) {
                    accg[mi][ni] = __builtin_amdgcn_mfma_f32_16x16x32_bf16(a[mi], b1, accg[mi][ni], 0, 0, 0);
                    accu[mi][ni] = __builtin_amdgcn_mfma_f32_16x16x32_bf16(a[mi], b3, accu[mi][ni], 0, 0, 0);
                }
            }
        }
    }
    // epilogue: silu(g)*u * topk_w  ->  act (bf16)
    int qr = lane >> 4, cl = lane & 15;
    #pragma unroll
    for (int mi = 0; mi < 4; ++mi) {
        #pragma unroll
        for (int r = 0; r < 4; ++r) {
            int m = wm + mi * 16 + qr * 4 + r;
            if (m0 + m < Ne) {
                int p = s_pair[m];
                float wt = s_wt[m];
                __hip_bfloat16* dst = act + (size_t)p * II + n0;
                #pragma unroll
                for (int ni = 0; ni < 4; ++ni) {
                    int n = wn + ni * 16 + cl;
                    float g = accg[mi][ni][r], u = accu[mi][ni][r];
                    float sg = g / (1.f + __expf(-g));
                    dst[n] = __float2bfloat16(wt * sg * u);
                }
            }
        }
    }
}

// ---------------------------------------------------------------------------
// Down-proj: yp[pair, h] = act[pair,:] . w2[e,:,h]   (bf16 out, no atomics)
// ---------------------------------------------------------------------------
#define DN_NT 16  // 2048/128
#define DN_MT 8

__global__ __launch_bounds__(256, 2) void down_mfma(
    const __hip_bfloat16* __restrict__ act, const float* __restrict__ w2,
    const int* __restrict__ counts, const int* __restrict__ list_pair,
    __hip_bfloat16* __restrict__ yp)
{
    int bx = blockIdx.x;
    int e   = bx / (DN_MT * DN_NT);
    int rem = bx % (DN_MT * DN_NT);
    int mt = rem / DN_NT, nt = rem % DN_NT;
    int Ne = counts[e];
    int m0 = mt * 128;
    if (m0 >= Ne) return;
    int n0 = nt * 128;

    __shared__ alignas(16) short Af[8192];
    __shared__ alignas(16) short Bf[8192];
    __shared__ int s_pair[128];

    const int tid = threadIdx.x;
    const int lane = tid & 63;
    const int w = tid >> 6;
    const int wm = (w & 1) * 64, wn = (w >> 1) * 64;

    if (tid < 128) {
        int m = m0 + tid;
        s_pair[tid] = (m < Ne) ? list_pair[e * TT + m] : 0;
    }

    ffrag acc[4][4];
    #pragma unroll
    for (int i = 0; i < 4; ++i)
        #pragma unroll
        for (int j = 0; j < 4; ++j) acc[i][j] = (ffrag)0.f;

    for (int k0 = 0; k0 < II; k0 += 64) {
        __syncthreads();
        // stage A: act is already bf16 -> direct 16B fragment-slot copies
        #pragma unroll
        for (int r = 0; r < 4; ++r) {
            int sidx = r * 256 + tid;               // fragment slot 0..1023
            int lf = sidx & 63, ss = (sidx >> 6) & 1, mtile = sidx >> 7;
            int m = mtile * 16 + (lf & 15), q = lf >> 4;
            int p = s_pair[m];
            *(uint4*)&Af[sidx * 8] =
                *(const uint4*)(act + (size_t)p * II + k0 + ss * 32 + q * 8);
        }
        {   // stage w2 tile
            int n = tid & 127, kp2 = tid >> 7;
            int ntile = n >> 4, nl = n & 15;
            const float* s2 = w2 + ((size_t)e * II + k0 + kp2 * 32) * HH + n0 + n;
            #pragma unroll
            for (int r = 0; r < 16; ++r) {
                int kp = kp2 * 16 + r;
                int k = kp * 2;
                float va = s2[(size_t)(2 * r) * HH], vb = s2[(size_t)(2 * r + 1) * HH];
                int s = k >> 5, q = (k >> 3) & 3;
                int slot = ((ntile * 2 + s) * 64 + nl + q * 16) * 8 + (kp & 3) * 2;
                *(unsigned*)&Bf[slot] = packbf(va, vb);
            }
        }
        __syncthreads();
        #pragma unroll
        for (int s = 0; s < 2; ++s) {
            bfrag a[4];
            #pragma unroll
            for (int mi = 0; mi < 4; ++mi)
                a[mi] = *(const bfrag*)&Af[(((wm >> 4) + mi) * 2 + s) * 64 * 8 + lane * 8];
            #pragma unroll
            for (int ni = 0; ni < 4; ++ni) {
                bfrag b = *(const bfrag*)&Bf[(((wn >> 4) + ni) * 2 + s) * 64 * 8 + lane * 8];
                #pragma unroll
                for (int mi = 0; mi < 4; ++mi)
                    acc[mi][ni] = __builtin_amdgcn_mfma_f32_16x16x32_bf16(a[mi], b, acc[mi][ni], 0, 0, 0);
            }
        }
    }
    int qr = lane >> 4, cl = lane & 15;
    #pragma unroll
    for (int mi = 0; mi < 4; ++mi) {
        #pragma unroll
        for (int r = 0; r < 4; ++r) {
            int m = wm + mi * 16 + qr * 4 + r;
            if (m0 + m < Ne) {
                int p = s_pair[m];
                __hip_bfloat16* dst = yp + (size_t)p * HH + n0;
                #pragma unroll
                for (int ni = 0; ni < 4; ++ni)
                    dst[wn + ni * 16 + cl] = __float2bfloat16(acc[mi][ni][r]);
            }
        }
    }
}

// ---------------------------------------------------------------------------
// Combine: y[t,h] = sum_{j<8} yp[t*8+j, h]   (weights already folded in act)
// ---------------------------------------------------------------------------
__global__ void combine_kernel(const __hip_bfloat16* __restrict__ yp, float* __restrict__ out) {
    int i = blockIdx.x * blockDim.x + threadIdx.x;   // 0 .. TT*HH
    int t = i >> 11, h = i & (HH - 1);
    const __hip_bfloat16* p = yp + (size_t)(t * TOPK) * HH + h;
    float s = 0.f;
    #pragma unroll
    for (int j = 0; j < TOPK; ++j) s += __bfloat162float(p[(size_t)j * HH]);
    out[i] = s;
}

// ---------------------------------------------------------------------------
extern "C" void kernel_launch(void* const* d_in, const int* in_sizes, int n_in,
                              void* d_out, int out_size, void* d_ws, size_t ws_size,
                              hipStream_t stream) {
    const float* x  = (const float*)d_in[0];  // [1,1024,2048]
    const float* gw = (const float*)d_in[1];  // [64,2048]
    const float* w1 = (const float*)d_in[2];  // [64,2048,768]
    const float* w3 = (const float*)d_in[3];  // [64,2048,768]
    const float* w2 = (const float*)d_in[4];  // [64,768,2048]
    float* out = (float*)d_out;               // [1,1024,2048] fp32

    // workspace layout
    char* ws = (char*)d_ws;
    int*   counts    = (int*)ws;                              // 1 KB
    int*   list_pair = (int*)(ws + 1024);                     // 256 KB
    float* list_wt   = (float*)(ws + 1024 + 262144);          // 256 KB
    __hip_bfloat16* act = (__hip_bfloat16*)(ws + 1024 + 2 * 262144);       // 8192*768*2  = 12.6 MB
    __hip_bfloat16* yp  = (__hip_bfloat16*)(ws + 1024 + 2 * 262144 +
                                            (size_t)NPAIR * II * 2);       // 8192*2048*2 = 33.6 MB

    zero_counts<<<1, EE, 0, stream>>>(counts);
    gate_kernel<<<TT, 64, 0, stream>>>(x, gw, counts, list_pair, list_wt);
    up_mfma<<<EE * UP_MT * UP_NT, 256, 0, stream>>>(x, w1, w3, counts, list_pair, list_wt, act);
    down_mfma<<<EE * DN_MT * DN_NT, 256, 0, stream>>>(act, w2, counts, list_pair, yp);
    combine_kernel<<<(TT * HH) / 256, 256, 0, stream>>>(yp, out);
}